// Round 1
// baseline (26.879 us; speedup 1.0000x reference)
//
#include <hip/hip_runtime.h>

#define N 4096
#define M 1024
#define D 64
#define MT 16          // m-values per thread
#define SPLITS 8       // N-chunks (block level)
#define ROWS_PER_WAVE (N / SPLITS / 4)   // 128

// Stage A: partial min over an N-chunk for a 16-m tile.
// grid = 64 m-tiles * 8 splits = 512 blocks, 256 threads (4 waves).
// lane = d (0..63); each wave takes a 128-row quarter of the block's chunk.
// Output: pout[s][m][d] partial mins (written into d_out+1 region, 2 MB).
__global__ __launch_bounds__(256) void k_minpart(const float* __restrict__ z,
                                                 const float* __restrict__ e,
                                                 float* __restrict__ pout) {
    const int bid  = blockIdx.x;
    const int mt   = bid & 63;   // m-tile id
    const int s    = bid >> 6;   // split id
    const int lane = threadIdx.x & 63;
    const int w    = threadIdx.x >> 6;
    const int m0   = mt * MT;

    float ev[MT];
#pragma unroll
    for (int j = 0; j < MT; ++j) ev[j] = e[(m0 + j) * D + lane];

    float acc[MT];
#pragma unroll
    for (int j = 0; j < MT; ++j) acc[j] = 3.4e38f;

    const int nbase = s * (N / SPLITS) + w * ROWS_PER_WAVE;
    const float* zp = z + nbase * D + lane;
#pragma unroll 4
    for (int r = 0; r < ROWS_PER_WAVE; ++r) {
        const float zv = zp[r * D];
#pragma unroll
        for (int j = 0; j < MT; ++j) {
            const float df = zv - ev[j];
            acc[j] = fminf(acc[j], df * df);
        }
    }

    __shared__ float lds[4][MT * 64];
#pragma unroll
    for (int j = 0; j < MT; ++j) lds[w][j * 64 + lane] = acc[j];
    __syncthreads();

    // 1024 sites per block, 256 threads -> 4 each; combine the 4 waves.
    for (int p = threadIdx.x; p < MT * 64; p += 256) {
        const float v = fminf(fminf(lds[0][p], lds[1][p]),
                              fminf(lds[2][p], lds[3][p]));
        pout[s * (M * D) + m0 * D + p] = v;   // coalesced
    }
}

// Stage B: final min over the 8 splits, then block-level sum.
// grid = 64 blocks * 256 threads; each thread handles 4 (m,d) sites.
__global__ __launch_bounds__(256) void k_minsum(const float* __restrict__ pout,
                                                float* __restrict__ bsums) {
    const int t = blockIdx.x * 256 + threadIdx.x;  // 16384 threads
    float local = 0.0f;
#pragma unroll
    for (int k = 0; k < 4; ++k) {
        const int site = t + k * 16384;
        float v = 3.4e38f;
#pragma unroll
        for (int si = 0; si < SPLITS; ++si)
            v = fminf(v, pout[si * (M * D) + site]);
        local += v;
    }
    // deterministic wave tree-reduce
#pragma unroll
    for (int off = 32; off > 0; off >>= 1)
        local += __shfl_down(local, off, 64);
    __shared__ float wsum[4];
    const int lane = threadIdx.x & 63, w = threadIdx.x >> 6;
    if (lane == 0) wsum[w] = local;
    __syncthreads();
    if (threadIdx.x == 0)
        bsums[blockIdx.x] = (wsum[0] + wsum[1]) + (wsum[2] + wsum[3]);
}

// Final: sum 64 block sums in one wave, scale by 1/(M*D).
__global__ void k_final(const float* __restrict__ bsums, float* __restrict__ out) {
    float v = bsums[threadIdx.x];
#pragma unroll
    for (int off = 32; off > 0; off >>= 1)
        v += __shfl_down(v, off, 64);
    if (threadIdx.x == 0) out[0] = v * (1.0f / (M * D));
}

// Elementwise: z_masked and z_copy. Runs LAST (overwrites the pout scratch).
__global__ __launch_bounds__(256) void k_mask(const float* __restrict__ z,
                                              const int* __restrict__ idx,
                                              float* __restrict__ out) {
    const int i = blockIdx.x * 256 + threadIdx.x;  // 262144 threads
    const float zv = z[i];
    const int row = i >> 6, d2 = i & 63;
    const float mv = (d2 < idx[row]) ? zv : 0.0f;
    out[1 + i] = mv;               // z_masked
    out[1 + N * D + i] = zv;       // z_copy
}

extern "C" void kernel_launch(void* const* d_in, const int* in_sizes, int n_in,
                              void* d_out, int out_size, void* d_ws, size_t ws_size,
                              hipStream_t stream) {
    const float* z   = (const float*)d_in[0];
    const float* e   = (const float*)d_in[1];
    const int*   idx = (const int*)d_in[2];
    float* out = (float*)d_out;
    float* pout  = out + 1;          // reuse z_masked/z_copy slots (2 MB) as scratch
    float* bsums = (float*)d_ws;     // needs only 256 B

    k_minpart<<<64 * SPLITS, 256, 0, stream>>>(z, e, pout);
    k_minsum<<<64, 256, 0, stream>>>(pout, bsums);
    k_final<<<1, 64, 0, stream>>>(bsums, out);
    k_mask<<<1024, 256, 0, stream>>>(z, idx, out);
}